// Round 11
// baseline (30.606 us; speedup 1.0000x reference)
//
#include <hip/hip_runtime.h>
#include <math.h>

constexpr int Hn = 18, Wn = 18, HWn = 324;
constexpr int WPB = HWn / 4;        // 81 waves per b-row (4 tiles/wave)
constexpr int TICK_STRIDE = 16;     // one counter per 64B line

// DPP row_ror rotate within each aligned 16-lane group: pure-VALU cross-lane.
template<int N>
__device__ __forceinline__ float ror16_f(float x) {
    return __int_as_float(__builtin_amdgcn_mov_dpp(
        __float_as_int(x), 0x120 | N, 0xF, 0xF, true));
}
template<int N>
__device__ __forceinline__ unsigned ror16_u(unsigned x) {
    return (unsigned)__builtin_amdgcn_mov_dpp(
        (int)x, 0x120 | N, 0xF, 0xF, true);
}
template<int N>
__device__ __forceinline__ int ror16_i(int x) {
    return __builtin_amdgcn_mov_dpp(x, 0x120 | N, 0xF, 0xF, true);
}

// Four tiles per wave; 16-lane group g owns tile wave*4+g (column layout).
// Fused normalization WITHOUT fences: psrw results are stored with
// agent-scope relaxed atomic stores (write-through to the device coherence
// point -> no dirty local cache state), a wave-local vmcnt(0) guarantees
// completion, then a relaxed agent-scope ticket atomicAdd. RMW total order
// at the coherence point makes all 81 waves' stores visible to the last
// arriver, which re-reads via agent-scope loads (protocol validated in R9;
// only the expensive __threadfence/L2-writeback is replaced).
__global__ __launch_bounds__(256, 6) void psrw_kernel(
    const float* __restrict__ cv, const int* __restrict__ peak,
    float* __restrict__ out, unsigned* __restrict__ tick, int BC)
{
    int gtid = blockIdx.x * 256 + threadIdx.x;
    int wave = gtid >> 6;
    int lane = threadIdx.x & 63;
    int g = lane >> 4;
    int l = lane & 15;
    int tile = wave * 4 + g;
    if (tile >= BC) return;

    const float* row = cv + (size_t)tile * HWn;
    int2 pk = ((const int2*)peak)[tile];
    int py = pk.x & 31, px = pk.y & 31;   // range-pin: enables mul24

    const float* colp = row + l;
    float c[21];
#pragma unroll
    for (int j = 0; j < 18; ++j) c[j] = colp[18 * j];   // imm-offset loads
    int lh = l >> 1, lb = l & 1;
    const float* tp = row + (lh * 18 + 16 + lb);
    c[18] = tp[0];
    c[19] = tp[144];
    bool v20 = (l < 4);
    c[20] = v20 ? tp[288] : 0.f;          // flat idx <= 323: always in-tile

    float cpk = row[py * Wn + px];        // peak value (uniform per group)

    // ---- Pass A: max + total sum; rect sum gathered by lanes 0..8 ----
    float m0 = -INFINITY, m1 = -INFINITY, s0 = 0.f, s1 = 0.f;
#pragma unroll
    for (int j = 0; j < 18; j += 2) { m0 = fmaxf(m0, c[j]); s0 += c[j]; }
#pragma unroll
    for (int j = 1; j < 18; j += 2) { m1 = fmaxf(m1, c[j]); s1 += c[j]; }
    m0 = fmaxf(m0, c[18]); s0 += c[18];
    m1 = fmaxf(m1, c[19]); s1 += c[19];
    m0 = fmaxf(m0, v20 ? c[20] : -INFINITY); s0 += c[20];
    float m = fmaxf(m0, m1);
    float s = s0 + s1;

    int ry0 = max(0, py - 1), ry1 = min(Hn - 1, py + 1);
    int rx0 = max(0, px - 1), rx1 = min(Wn - 1, px + 1);
    float rectc = 0.f;
    if (l < 9) {
        int q = (l * 11) >> 5;            // l/3 for l<=8
        int r = l - 3 * q;
        int ry = ry0 + q, rx = rx0 + r;
        if (ry <= ry1 && rx <= rx1) rectc = row[ry * Wn + rx];  // L1 hit
    }
    s -= rectc;                           // fold rect removal into reduction
    s += ror16_f<8>(s);  m = fmaxf(m, ror16_f<8>(m));
    s += ror16_f<4>(s);  m = fmaxf(m, ror16_f<4>(m));
    s += ror16_f<2>(s);  m = fmaxf(m, ror16_f<2>(m));
    s += ror16_f<1>(s);  m = fmaxf(m, ror16_f<1>(m));
    int n_pri = HWn - (ry1 - ry0 + 1) * (rx1 - rx0 + 1);
    float mean_pri = s / (float)n_pri;    // IEEE: feeds the keep-compare cliff

    // ---- Pass B: dminb = min over {c<=mean_pri} of (d2-1), unsigned ----
    int dxl = l - px;
    int dx2m1 = dxl * dxl - 1;
    unsigned A = (unsigned)(py * py + dx2m1);  // dy = -py at j=0
    int Bs = 1 - 2 * py;                       // A += 2*dy+1 per j
    unsigned dminb = 0xFFFFFFFFu;
#pragma unroll
    for (int j = 0; j < 18; ++j) {
        unsigned t = min(dminb, A);
        dminb = (c[j] <= mean_pri) ? t : dminb;
        A += (unsigned)Bs; Bs += 2;
    }
    int dyt = lh - py;
    int dxt = 16 + lb - px;
    int dxt2m1 = dxt * dxt - 1;
#pragma unroll
    for (int s2 = 0; s2 < 3; ++s2) {
        int dy = dyt + 8 * s2;
        unsigned dd = (unsigned)(dy * dy + dxt2m1);
        if (s2 == 2 && !v20) dd = 0x7FFFFFFFu;   // invalid slot: far, not in-disk
        unsigned t = min(dminb, dd);
        dminb = (c[18 + s2] <= mean_pri) ? t : dminb;
    }
    dminb = min(dminb, ror16_u<8>(dminb));
    dminb = min(dminb, ror16_u<4>(dminb));
    dminb = min(dminb, ror16_u<2>(dminb));
    dminb = min(dminb, ror16_u<1>(dminb));

    // width = sqrt(dmin) (sentinel 100); disk test d2 <= clip(dmin,2,20) exact
    float width = (dminb > 577u) ? 100.f
                                 : __builtin_amdgcn_sqrtf((float)(dminb + 1u));
    unsigned rad2m1 = min(max(dminb, 1u), 19u);

    // ---- Pass C: survivors (d2-1 > rad2m1): sum, sumsq, in-disk count ----
    float sd0 = 0.f, sd1 = 0.f, ssd = 0.f;
    int cnt = 0;
    unsigned A2 = (unsigned)(py * py + dx2m1);
    int Bs2 = 1 - 2 * py;
#pragma unroll
    for (int j = 0; j < 18; ++j) {
        bool in = (A2 <= rad2m1);         // peak: 0xFFFFFFFF -> "survivor" (fixed below)
        float cm = in ? 0.f : c[j];
        if (j & 1) sd1 += cm; else sd0 += cm;
        ssd = fmaf(cm, cm, ssd);
        cnt += in ? 1 : 0;
        A2 += (unsigned)Bs2; Bs2 += 2;
    }
#pragma unroll
    for (int s2 = 0; s2 < 3; ++s2) {
        int dy = dyt + 8 * s2;
        unsigned dd = (unsigned)(dy * dy + dxt2m1);
        if (s2 == 2 && !v20) dd = 0x7FFFFFFFu;
        bool in = (dd <= rad2m1);
        float cm = in ? 0.f : c[18 + s2];
        if (s2 & 1) sd1 += cm; else sd0 += cm;
        ssd = fmaf(cm, cm, ssd);
        cnt += in ? 1 : 0;
    }
    float sd = sd0 + sd1;
    sd += ror16_f<8>(sd);  ssd += ror16_f<8>(ssd);  cnt += ror16_i<8>(cnt);
    sd += ror16_f<4>(sd);  ssd += ror16_f<4>(ssd);  cnt += ror16_i<4>(cnt);
    sd += ror16_f<2>(sd);  ssd += ror16_f<2>(ssd);  cnt += ror16_i<2>(cnt);
    sd += ror16_f<1>(sd);  ssd += ror16_f<1>(ssd);  cnt += ror16_i<1>(cnt);
    // peak correction: it is always in-disk (d2=0 <= rad2 since rad2>=2)
    sd -= cpk;
    ssd = fmaf(-cpk, cpk, ssd);
    float n = (float)(HWn - 1 - cnt);
    float mean_s = sd * __builtin_amdgcn_rcpf(n);
    float var_s = fmaf(-sd, mean_s, ssd) * __builtin_amdgcn_rcpf(n - 1.f);
    float psrw = (m - mean_s) * __builtin_amdgcn_rcpf(fmaf(var_s, width, 1e-16f));

    // ---- Store psrw at device coherence point (no dirty local cache) ----
    if (l == 0)
        __hip_atomic_store((unsigned*)&out[tile], __float_as_uint(psrw),
                           __ATOMIC_RELAXED, __HIP_MEMORY_SCOPE_AGENT);

    // ---- Fused normalization: 81st arriver of each b normalizes the row ----
    int b = wave / WPB;                   // all 4 tiles of a wave share b
    asm volatile("s_waitcnt vmcnt(0)" ::: "memory");  // our stores complete
    unsigned tk = 0;
    if (lane == 0)
        tk = __hip_atomic_fetch_add(&tick[b * TICK_STRIDE], 1u,
                                    __ATOMIC_RELAXED, __HIP_MEMORY_SCOPE_AGENT);
    tk = (unsigned)__shfl((int)tk, 0, 64);
    if (tk == (unsigned)(WPB - 1)) {      // exactly one wave per b (tick zeroed)
        float* rowo = out + (size_t)b * HWn;
        float vals[6];
        float sn = 0.f;
#pragma unroll
        for (int k = 0; k < 6; ++k) {
            int idx = lane + 64 * k;
            float v = 0.f;
            if (idx < HWn)
                v = __uint_as_float(__hip_atomic_load(
                        (const unsigned*)&rowo[idx],
                        __ATOMIC_RELAXED, __HIP_MEMORY_SCOPE_AGENT));
            vals[k] = v;
            sn += v;
        }
#pragma unroll
        for (int o = 32; o; o >>= 1) sn += __shfl_xor(sn, o, 64);
        float idv = 1.f / (sn / 324.f + 1e-8f);
#pragma unroll
        for (int k = 0; k < 6; ++k) {
            int idx = lane + 64 * k;
            if (idx < HWn) rowo[idx] = vals[k] * idv;
        }
    }
}

extern "C" void kernel_launch(void* const* d_in, const int* in_sizes, int n_in,
                              void* d_out, int out_size, void* d_ws, size_t ws_size,
                              hipStream_t stream) {
    const float* cv  = (const float*)d_in[0];
    const int* peak  = (const int*)d_in[1];
    // d_in[2]/d_in[3] (mesh_y/mesh_x) are broadcast index grids — recomputed.
    float* out = (float*)d_out;
    unsigned* tick = (unsigned*)d_ws;

    int BC = in_sizes[1] / 2;               // 82944 tiles
    int B = out_size / HWn;                 // 256 b-rows
    // Zero the ticket array every launch (graph-capture-legal, 16 KB).
    hipMemsetAsync(tick, 0, (size_t)B * TICK_STRIDE * sizeof(unsigned), stream);

    int waves = (BC + 3) / 4;               // 4 tiles per wave; 81 waves per b
    int blocks = (waves + 3) / 4;           // 4 waves per 256-thread block
    psrw_kernel<<<blocks, 256, 0, stream>>>(cv, peak, out, tick, BC);
}

// Round 12
// 25.303 us; speedup vs baseline: 1.2096x; 1.2096x over previous
//
#include <hip/hip_runtime.h>
#include <math.h>

constexpr int Hn = 18, Wn = 18, HWn = 324;

// DPP row_ror rotate within each aligned 16-lane group: pure-VALU cross-lane.
template<int N>
__device__ __forceinline__ float ror16_f(float x) {
    return __int_as_float(__builtin_amdgcn_mov_dpp(
        __float_as_int(x), 0x120 | N, 0xF, 0xF, true));
}
template<int N>
__device__ __forceinline__ unsigned ror16_u(unsigned x) {
    return (unsigned)__builtin_amdgcn_mov_dpp(
        (int)x, 0x120 | N, 0xF, 0xF, true);
}
template<int N>
__device__ __forceinline__ int ror16_i(int x) {
    return __builtin_amdgcn_mov_dpp(x, 0x120 | N, 0xF, 0xF, true);
}

// Four tiles per wave; 16-lane group g owns tile wave*4+g (column layout:
// lane l owns column x=l, slots j=0..17 = element j*18+l; tails slots 18-20).
// Pass C is a 9x9 peak-window gather: the dynamic disk (radius<=4.5, d2<=20)
// lies entirely within |dy|<=4,|dx|<=4, so survivor stats = totals (from
// pass A) minus window in-disk stats. Lane l covers column offset ox=l-4
// (lanes 9-15: ox^2>=25 > rad2 -> auto-excluded); rows via a clamped 9-row
// window (always in-tile -> imm-offset loads, no OOB). Peak cell excluded
// by the d2-1 unsigned wrap; mean_pri reduction bit-identical to R10.
__global__ __launch_bounds__(256) void psrw_kernel(
    const float* __restrict__ cv, const int* __restrict__ peak,
    float* __restrict__ out, int BC)
{
    int gtid = blockIdx.x * 256 + threadIdx.x;
    int wave = gtid >> 6;
    int lane = threadIdx.x & 63;
    int g = lane >> 4;
    int l = lane & 15;
    int tile = wave * 4 + g;
    if (tile >= BC) return;

    const float* row = cv + (size_t)tile * HWn;
    int2 pk = ((const int2*)peak)[tile];
    int py = pk.x & 31, px = pk.y & 31;   // range-pin: enables mul24

    const float* colp = row + l;
    float c[21];
#pragma unroll
    for (int j = 0; j < 18; ++j) c[j] = colp[18 * j];   // imm-offset loads
    int lh = l >> 1, lb = l & 1;
    const float* tp = row + (lh * 18 + 16 + lb);
    c[18] = tp[0];
    c[19] = tp[144];
    bool v20 = (l < 4);
    c[20] = v20 ? tp[288] : 0.f;          // flat idx <= 323: always in-tile

    float cpk = row[py * Wn + px];        // peak value (uniform per group)

    // ---- 9x9 window loads (early issue; consumed in pass C) ----
    int ox = l - 4;                       // lanes 9-15: ox^2>=25 -> never in-disk
    int xraw = px + ox;
    int xs = min(max(xraw, 0), 17);       // clamped column (safe address)
    bool xv = ((unsigned)xraw < 18u);
    int ystart = min(max(py - 4, 0), 9);  // rows ystart..ystart+8 always in-grid
    const float* wbase = row + ystart * 18 + xs;
    float wv[9];
#pragma unroll
    for (int k = 0; k < 9; ++k) wv[k] = wbase[18 * k];
    int ox2m1 = ox * ox - 1;
    int dyb = ystart - py;                // oy = dyb + k

    // ---- Pass A: max + sum + sumsq; rect sum gathered by lanes 0..8 ----
    float m0 = -INFINITY, m1 = -INFINITY, s0 = 0.f, s1 = 0.f, q0 = 0.f, q1 = 0.f;
#pragma unroll
    for (int j = 0; j < 18; j += 2) {
        m0 = fmaxf(m0, c[j]); s0 += c[j]; q0 = fmaf(c[j], c[j], q0);
    }
#pragma unroll
    for (int j = 1; j < 18; j += 2) {
        m1 = fmaxf(m1, c[j]); s1 += c[j]; q1 = fmaf(c[j], c[j], q1);
    }
    m0 = fmaxf(m0, c[18]); s0 += c[18]; q0 = fmaf(c[18], c[18], q0);
    m1 = fmaxf(m1, c[19]); s1 += c[19]; q1 = fmaf(c[19], c[19], q1);
    m0 = fmaxf(m0, v20 ? c[20] : -INFINITY); s0 += c[20]; q0 = fmaf(c[20], c[20], q0);
    float m = fmaxf(m0, m1);
    float s = s0 + s1;
    float q = q0 + q1;

    int ry0 = max(0, py - 1), ry1 = min(Hn - 1, py + 1);
    int rx0 = max(0, px - 1), rx1 = min(Wn - 1, px + 1);
    float rectc = 0.f;
    if (l < 9) {
        int qd = (l * 11) >> 5;           // l/3 for l<=8
        int r = l - 3 * qd;
        int ry = ry0 + qd, rx = rx0 + r;
        if (ry <= ry1 && rx <= rx1) rectc = row[ry * Wn + rx];  // L1 hit
    }
    float sm = s - rectc;                 // rect folded pre-reduction (bit-identical
                                          // mean_pri path vs R10)
    sm += ror16_f<8>(sm); m = fmaxf(m, ror16_f<8>(m));
    q  += ror16_f<8>(q);  rectc += ror16_f<8>(rectc);
    sm += ror16_f<4>(sm); m = fmaxf(m, ror16_f<4>(m));
    q  += ror16_f<4>(q);  rectc += ror16_f<4>(rectc);
    sm += ror16_f<2>(sm); m = fmaxf(m, ror16_f<2>(m));
    q  += ror16_f<2>(q);  rectc += ror16_f<2>(rectc);
    sm += ror16_f<1>(sm); m = fmaxf(m, ror16_f<1>(m));
    q  += ror16_f<1>(q);  rectc += ror16_f<1>(rectc);
    int n_pri = HWn - (ry1 - ry0 + 1) * (rx1 - rx0 + 1);
    float mean_pri = sm / (float)n_pri;   // IEEE: feeds the keep-compare cliff
    float s_total = sm + rectc;           // raw tile sum (smooth path only)

    // ---- Pass B: dminb = min over {c<=mean_pri} of (d2-1), unsigned ----
    // ddm1 = dy^2 + (dx^2-1); peak (d2=0) wraps to 0xFFFFFFFF -> auto-excluded.
    int dxl = l - px;
    int dx2m1 = dxl * dxl - 1;
    unsigned A = (unsigned)(py * py + dx2m1);  // dy = -py at j=0
    int Bs = 1 - 2 * py;                       // A += 2*dy+1 per j
    unsigned dminb = 0xFFFFFFFFu;
#pragma unroll
    for (int j = 0; j < 18; ++j) {
        unsigned t = min(dminb, A);
        dminb = (c[j] <= mean_pri) ? t : dminb;
        A += (unsigned)Bs; Bs += 2;
    }
    int dyt = lh - py;
    int dxt = 16 + lb - px;
    int dxt2m1 = dxt * dxt - 1;
#pragma unroll
    for (int s2 = 0; s2 < 3; ++s2) {
        int dy = dyt + 8 * s2;
        unsigned dd = (unsigned)(dy * dy + dxt2m1);
        if (s2 == 2 && !v20) dd = 0x7FFFFFFFu;   // invalid slot: far, not in-disk
        unsigned t = min(dminb, dd);
        dminb = (c[18 + s2] <= mean_pri) ? t : dminb;
    }
    dminb = min(dminb, ror16_u<8>(dminb));
    dminb = min(dminb, ror16_u<4>(dminb));
    dminb = min(dminb, ror16_u<2>(dminb));
    dminb = min(dminb, ror16_u<1>(dminb));

    // width = sqrt(dmin) (sentinel 100); disk test d2 <= clip(dmin,2,20) exact
    float width = (dminb > 577u) ? 100.f
                                 : __builtin_amdgcn_sqrtf((float)(dminb + 1u));
    unsigned rad2m1 = min(max(dminb, 1u), 19u);

    // ---- Pass C: in-disk stats from the 9x9 window; survivors by subtraction ----
    float ds = 0.f, dss = 0.f;
    int dcnt = 0;
#pragma unroll
    for (int k = 0; k < 9; ++k) {
        int oy = dyb + k;
        unsigned d2m1 = (unsigned)(oy * oy + ox2m1);  // peak: -1 -> wraps, excluded
        bool val = (d2m1 <= rad2m1) & xv;             // in-disk & real column
        float cm = val ? wv[k] : 0.f;
        ds += cm;
        dss = fmaf(cm, cm, dss);
        dcnt += val ? 1 : 0;
    }
    ds += ror16_f<8>(ds); dss += ror16_f<8>(dss); dcnt += ror16_i<8>(dcnt);
    ds += ror16_f<4>(ds); dss += ror16_f<4>(dss); dcnt += ror16_i<4>(dcnt);
    ds += ror16_f<2>(ds); dss += ror16_f<2>(dss); dcnt += ror16_i<2>(dcnt);
    ds += ror16_f<1>(ds); dss += ror16_f<1>(dss); dcnt += ror16_i<1>(dcnt);

    // survivors = all - (disk excl. peak) - peak
    float sd = s_total - ds - cpk;
    float ssd = fmaf(-cpk, cpk, q - dss);
    float n = (float)(HWn - 1 - dcnt);
    float mean_s = sd * __builtin_amdgcn_rcpf(n);
    float var_s = fmaf(-sd, mean_s, ssd) * __builtin_amdgcn_rcpf(n - 1.f);
    float psrw = (m - mean_s) * __builtin_amdgcn_rcpf(fmaf(var_s, width, 1e-16f));
    if (l == 0) out[tile] = psrw;
}

// Normalize each b-row of C=324 psrw values by (mean + 1e-8), in place.
__global__ __launch_bounds__(256) void norm_kernel(float* __restrict__ out, int B)
{
    int gtid = blockIdx.x * 256 + threadIdx.x;
    int wave = gtid >> 6;
    int lane = threadIdx.x & 63;
    if (wave >= B) return;
    float* row = out + (size_t)wave * HWn;
    float4 v0 = reinterpret_cast<float4*>(row)[lane];
    bool has2 = lane < 17;
    float4 v1 = make_float4(0.f, 0.f, 0.f, 0.f);
    if (has2) v1 = reinterpret_cast<float4*>(row)[64 + lane];
    float s = (v0.x + v0.y) + (v0.z + v0.w) + ((v1.x + v1.y) + (v1.z + v1.w));
#pragma unroll
    for (int o = 32; o; o >>= 1) s += __shfl_xor(s, o, 64);
    float denom = s / 324.0f + 1e-8f;
    v0.x /= denom; v0.y /= denom; v0.z /= denom; v0.w /= denom;
    reinterpret_cast<float4*>(row)[lane] = v0;
    if (has2) {
        v1.x /= denom; v1.y /= denom; v1.z /= denom; v1.w /= denom;
        reinterpret_cast<float4*>(row)[64 + lane] = v1;
    }
}

extern "C" void kernel_launch(void* const* d_in, const int* in_sizes, int n_in,
                              void* d_out, int out_size, void* d_ws, size_t ws_size,
                              hipStream_t stream) {
    const float* cv  = (const float*)d_in[0];
    const int* peak  = (const int*)d_in[1];
    // d_in[2]/d_in[3] (mesh_y/mesh_x) are broadcast index grids — recomputed.
    float* out = (float*)d_out;

    int BC = in_sizes[1] / 2;               // 82944 tiles
    int waves = (BC + 3) / 4;               // 4 tiles per wave
    int blocks1 = (waves + 3) / 4;          // 4 waves per 256-thread block
    psrw_kernel<<<blocks1, 256, 0, stream>>>(cv, peak, out, BC);

    int B = out_size / HWn;
    int blocks2 = (B + 3) / 4;
    norm_kernel<<<blocks2, 256, 0, stream>>>(out, B);
}

// Round 13
// 24.665 us; speedup vs baseline: 1.2409x; 1.0258x over previous
//
#include <hip/hip_runtime.h>
#include <math.h>

constexpr int Hn = 18, Wn = 18, HWn = 324;

// DPP row_ror rotate within each aligned 16-lane group: pure-VALU cross-lane.
template<int N>
__device__ __forceinline__ float ror16_f(float x) {
    return __int_as_float(__builtin_amdgcn_mov_dpp(
        __float_as_int(x), 0x120 | N, 0xF, 0xF, true));
}
template<int N>
__device__ __forceinline__ unsigned ror16_u(unsigned x) {
    return (unsigned)__builtin_amdgcn_mov_dpp(
        (int)x, 0x120 | N, 0xF, 0xF, true);
}
template<int N>
__device__ __forceinline__ int ror16_i(int x) {
    return __builtin_amdgcn_mov_dpp(x, 0x120 | N, 0xF, 0xF, true);
}

// Four tiles per wave; 16-lane group g owns tile wave*4+g.
// Pass A (max/sum/sumsq) is folded into the column loads -> no c[21] array.
// Pass B runs on the 9x9 peak window only (all cells outside the |dy|<=4,
// |dx|<=4 core have d2 >= 25, so window-dmin <= 25 certifies the global
// min); the astronomically-rare uncertified case falls back to the exact
// full-tile scan (group-uniform branch). Pass C = R12's window subtraction.
__global__ __launch_bounds__(256) void psrw_kernel(
    const float* __restrict__ cv, const int* __restrict__ peak,
    float* __restrict__ out, int BC)
{
    int gtid = blockIdx.x * 256 + threadIdx.x;
    int wave = gtid >> 6;
    int lane = threadIdx.x & 63;
    int l = lane & 15;
    int tile = wave * 4 + (lane >> 4);
    if (tile >= BC) return;

    const float* row = cv + (size_t)tile * HWn;
    int2 pk = ((const int2*)peak)[tile];
    int py = pk.x & 31, px = pk.y & 31;   // range-pin: enables mul24

    // ---- 9x9 window loads (early issue) ----
    int ox = l - 4;                       // lanes 9-15: ox^2>=25 -> never in-disk
    int xraw = px + ox;
    int xs = min(max(xraw, 0), 17);       // clamped column (safe address)
    bool xv = ((unsigned)xraw < 18u);
    int ystart = min(max(py - 4, 0), 9);  // rows ystart..ystart+8 always in-grid
    const float* wbase = row + ystart * 18 + xs;
    float wv[9];
#pragma unroll
    for (int k = 0; k < 9; ++k) wv[k] = wbase[18 * k];
    int ox2m1 = ox * ox - 1;
    int dyb = ystart - py;                // oy = dyb + k

    float cpk = row[py * Wn + px];        // peak value (uniform per group)

    // ---- Pass A fused into column loads: max + sum + sumsq ----
    const float* colp = row + l;
    float m0 = -INFINITY, m1 = -INFINITY, s0 = 0.f, s1 = 0.f, q0 = 0.f, q1 = 0.f;
#pragma unroll
    for (int j = 0; j < 18; j += 2) {
        float a = colp[18 * j];
        float b = colp[18 * (j + 1)];
        m0 = fmaxf(m0, a); s0 += a; q0 = fmaf(a, a, q0);
        m1 = fmaxf(m1, b); s1 += b; q1 = fmaf(b, b, q1);
    }
    int lh = l >> 1, lb = l & 1;
    const float* tp = row + (lh * 18 + 16 + lb);
    float c18 = tp[0];
    float c19 = tp[144];
    bool v20 = (l < 4);
    float c20 = v20 ? tp[288] : 0.f;      // flat idx <= 323: always in-tile
    m0 = fmaxf(m0, c18); s0 += c18; q0 = fmaf(c18, c18, q0);
    m1 = fmaxf(m1, c19); s1 += c19; q1 = fmaf(c19, c19, q1);
    m0 = fmaxf(m0, v20 ? c20 : -INFINITY); s0 += c20; q0 = fmaf(c20, c20, q0);
    float m = fmaxf(m0, m1);
    float s = s0 + s1;
    float q = q0 + q1;

    int ry0 = max(0, py - 1), ry1 = min(Hn - 1, py + 1);
    int rx0 = max(0, px - 1), rx1 = min(Wn - 1, px + 1);
    float rectc = 0.f;
    if (l < 9) {
        int qd = (l * 11) >> 5;           // l/3 for l<=8
        int r = l - 3 * qd;
        int ry = ry0 + qd, rx = rx0 + r;
        if (ry <= ry1 && rx <= rx1) rectc = row[ry * Wn + rx];  // L1 hit
    }
    float sm = s - rectc;                 // rect folded pre-reduction
    sm += ror16_f<8>(sm); m = fmaxf(m, ror16_f<8>(m));
    q  += ror16_f<8>(q);  rectc += ror16_f<8>(rectc);
    sm += ror16_f<4>(sm); m = fmaxf(m, ror16_f<4>(m));
    q  += ror16_f<4>(q);  rectc += ror16_f<4>(rectc);
    sm += ror16_f<2>(sm); m = fmaxf(m, ror16_f<2>(m));
    q  += ror16_f<2>(q);  rectc += ror16_f<2>(rectc);
    sm += ror16_f<1>(sm); m = fmaxf(m, ror16_f<1>(m));
    q  += ror16_f<1>(q);  rectc += ror16_f<1>(rectc);
    int n_pri = HWn - (ry1 - ry0 + 1) * (rx1 - rx0 + 1);
    float mean_pri = sm / (float)n_pri;   // IEEE: feeds the keep-compare cliff
    float s_total = sm + rectc;           // raw tile sum (smooth path only)

    // ---- Pass B (windowed): dminb = min over window keep cells of (d2-1) ----
    // Peak cell: d2-1 = -1 wraps to 0xFFFFFFFF -> auto-excluded.
    unsigned dminb = 0xFFFFFFFFu;
#pragma unroll
    for (int k = 0; k < 9; ++k) {
        int oy = dyb + k;
        unsigned d2m1 = (unsigned)(oy * oy + ox2m1);
        bool keep = (wv[k] <= mean_pri) & xv;
        unsigned t = min(dminb, d2m1);
        dminb = keep ? t : dminb;
    }
    dminb = min(dminb, ror16_u<8>(dminb));
    dminb = min(dminb, ror16_u<4>(dminb));
    dminb = min(dminb, ror16_u<2>(dminb));
    dminb = min(dminb, ror16_u<1>(dminb));

    // Certification: cells outside the window core have d2 >= 25, so
    // dminb <= 24 (d2 <= 25) is globally exact. Else: exact full scan
    // (group-uniform branch; ~2^-45 probability on this data).
    if (__builtin_expect(dminb > 24u, 0)) {
        int dxl = l - px;
        int dx2m1c = dxl * dxl - 1;
        unsigned A = (unsigned)(py * py + dx2m1c);
        int Bs = 1 - 2 * py;
        unsigned dmf = 0xFFFFFFFFu;
#pragma unroll
        for (int j = 0; j < 18; ++j) {
            float cval = colp[18 * j];    // L1-resident reload
            unsigned t = min(dmf, A);
            dmf = (cval <= mean_pri) ? t : dmf;
            A += (unsigned)Bs; Bs += 2;
        }
        int dyt = lh - py;
        int dxt = 16 + lb - px;
        int dxt2m1 = dxt * dxt - 1;
        float ctail[3] = {c18, c19, c20};
#pragma unroll
        for (int s2 = 0; s2 < 3; ++s2) {
            int dy = dyt + 8 * s2;
            unsigned dd = (unsigned)(dy * dy + dxt2m1);
            if (s2 == 2 && !v20) dd = 0x7FFFFFFFu;
            unsigned t = min(dmf, dd);
            dmf = (ctail[s2] <= mean_pri) ? t : dmf;
        }
        dmf = min(dmf, ror16_u<8>(dmf));
        dmf = min(dmf, ror16_u<4>(dmf));
        dmf = min(dmf, ror16_u<2>(dmf));
        dmf = min(dmf, ror16_u<1>(dmf));
        dminb = dmf;
    }

    // width = sqrt(dmin) (sentinel 100); disk test d2 <= clip(dmin,2,20) exact
    float width = (dminb > 577u) ? 100.f
                                 : __builtin_amdgcn_sqrtf((float)(dminb + 1u));
    unsigned rad2m1 = min(max(dminb, 1u), 19u);

    // ---- Pass C: in-disk stats from the window; survivors by subtraction ----
    float ds = 0.f, dss = 0.f;
    int dcnt = 0;
#pragma unroll
    for (int k = 0; k < 9; ++k) {
        int oy = dyb + k;
        unsigned d2m1 = (unsigned)(oy * oy + ox2m1);  // peak wraps -> excluded
        bool val = (d2m1 <= rad2m1) & xv;             // in-disk & real column
        float cm = val ? wv[k] : 0.f;
        ds += cm;
        dss = fmaf(cm, cm, dss);
        dcnt += val ? 1 : 0;
    }
    ds += ror16_f<8>(ds); dss += ror16_f<8>(dss); dcnt += ror16_i<8>(dcnt);
    ds += ror16_f<4>(ds); dss += ror16_f<4>(dss); dcnt += ror16_i<4>(dcnt);
    ds += ror16_f<2>(ds); dss += ror16_f<2>(dss); dcnt += ror16_i<2>(dcnt);
    ds += ror16_f<1>(ds); dss += ror16_f<1>(dss); dcnt += ror16_i<1>(dcnt);

    // survivors = all - (disk excl. peak) - peak
    float sd = s_total - ds - cpk;
    float ssd = fmaf(-cpk, cpk, q - dss);
    float n = (float)(HWn - 1 - dcnt);
    float mean_s = sd * __builtin_amdgcn_rcpf(n);
    float var_s = fmaf(-sd, mean_s, ssd) * __builtin_amdgcn_rcpf(n - 1.f);
    float psrw = (m - mean_s) * __builtin_amdgcn_rcpf(fmaf(var_s, width, 1e-16f));
    if (l == 0) out[tile] = psrw;
}

// Normalize each b-row of C=324 psrw values by (mean + 1e-8), in place.
__global__ __launch_bounds__(256) void norm_kernel(float* __restrict__ out, int B)
{
    int gtid = blockIdx.x * 256 + threadIdx.x;
    int wave = gtid >> 6;
    int lane = threadIdx.x & 63;
    if (wave >= B) return;
    float* row = out + (size_t)wave * HWn;
    float4 v0 = reinterpret_cast<float4*>(row)[lane];
    bool has2 = lane < 17;
    float4 v1 = make_float4(0.f, 0.f, 0.f, 0.f);
    if (has2) v1 = reinterpret_cast<float4*>(row)[64 + lane];
    float s = (v0.x + v0.y) + (v0.z + v0.w) + ((v1.x + v1.y) + (v1.z + v1.w));
#pragma unroll
    for (int o = 32; o; o >>= 1) s += __shfl_xor(s, o, 64);
    float denom = s / 324.0f + 1e-8f;
    v0.x /= denom; v0.y /= denom; v0.z /= denom; v0.w /= denom;
    reinterpret_cast<float4*>(row)[lane] = v0;
    if (has2) {
        v1.x /= denom; v1.y /= denom; v1.z /= denom; v1.w /= denom;
        reinterpret_cast<float4*>(row)[64 + lane] = v1;
    }
}

extern "C" void kernel_launch(void* const* d_in, const int* in_sizes, int n_in,
                              void* d_out, int out_size, void* d_ws, size_t ws_size,
                              hipStream_t stream) {
    const float* cv  = (const float*)d_in[0];
    const int* peak  = (const int*)d_in[1];
    // d_in[2]/d_in[3] (mesh_y/mesh_x) are broadcast index grids — recomputed.
    float* out = (float*)d_out;

    int BC = in_sizes[1] / 2;               // 82944 tiles
    int waves = (BC + 3) / 4;               // 4 tiles per wave
    int blocks1 = (waves + 3) / 4;          // 4 waves per 256-thread block
    psrw_kernel<<<blocks1, 256, 0, stream>>>(cv, peak, out, BC);

    int B = out_size / HWn;
    int blocks2 = (B + 3) / 4;
    norm_kernel<<<blocks2, 256, 0, stream>>>(out, B);
}